// Round 17
// baseline (551.598 us; speedup 1.0000x reference)
//
#include <hip/hip_runtime.h>
#include <hip/hip_bf16.h>
#include <stdint.h>

typedef int i32x4 __attribute__((ext_vector_type(4)));
typedef float f32x4 __attribute__((ext_vector_type(4)));

#define K_DIM 2048
#define M_DIM 8192   // B*S = 4*2048 tokens
#define N_DIM 8192   // D_OUT
#define QBF   127.0f
#define EPSF  1e-5f
#define NT    32     // K_DIM / 64 sub-tiles (BK=64)

__device__ __forceinline__ void load_lds16(const void* gsrc, void* ldst) {
    __builtin_amdgcn_global_load_lds(
        (__attribute__((address_space(1))) void*)gsrc,
        (__attribute__((address_space(3))) void*)ldst,
        16, 0, 0);
}

// ---------- Kernel 1 (fused): blocks 0..8191 quantize x rows; 8192..10239 |W| sums --
__global__ __launch_bounds__(256) void k_prep(const float* __restrict__ x,
                                              const float* __restrict__ w,
                                              uint* __restrict__ xq,
                                              float* __restrict__ alpha,
                                              float* __restrict__ partial) {
    __shared__ float red[256];
    int t = threadIdx.x, bid = blockIdx.x;
    if (bid >= 8192) {
        // ---- |W| partial sums (deterministic) ----
        int b = bid - 8192;
        const float4* w4 = (const float4*)w;
        size_t base = (size_t)b * 2048;
        float s = 0.f;
#pragma unroll
        for (int j = 0; j < 8; ++j) {
            float4 v = w4[base + j * 256 + t];
            s += fabsf(v.x) + fabsf(v.y) + fabsf(v.z) + fabsf(v.w);
        }
        red[t] = s; __syncthreads();
        for (int off = 128; off > 0; off >>= 1) {
            if (t < off) red[t] += red[t + off];
            __syncthreads();
        }
        if (t == 0) partial[b] = red[0];
        return;
    }
    // ---- per-token absmax quantize ----
    int row = bid;
    const float4* x4 = (const float4*)x + (size_t)row * 512;
    float4 v0 = x4[t], v1 = x4[t + 256];
    float m = fmaxf(fmaxf(fabsf(v0.x), fabsf(v0.y)), fmaxf(fabsf(v0.z), fabsf(v0.w)));
    m = fmaxf(m, fmaxf(fmaxf(fabsf(v1.x), fabsf(v1.y)), fmaxf(fabsf(v1.z), fabsf(v1.w))));
    red[t] = m; __syncthreads();
    for (int off = 128; off > 0; off >>= 1) {
        if (t < off) red[t] = fmaxf(red[t], red[t + off]);
        __syncthreads();
    }
    float a = red[0];
    if (t == 0) alpha[row] = a;
    float den = fmaxf(a, EPSF);
    uint* q = xq + (size_t)row * 512;
    int q0 = (int)fminf(fmaxf(rintf(v0.x * QBF / den), -QBF), QBF);
    int q1 = (int)fminf(fmaxf(rintf(v0.y * QBF / den), -QBF), QBF);
    int q2 = (int)fminf(fmaxf(rintf(v0.z * QBF / den), -QBF), QBF);
    int q3 = (int)fminf(fmaxf(rintf(v0.w * QBF / den), -QBF), QBF);
    q[t] = (q0 & 255) | ((q1 & 255) << 8) | ((q2 & 255) << 16) | ((q3 & 255) << 24);
    q0 = (int)fminf(fmaxf(rintf(v1.x * QBF / den), -QBF), QBF);
    q1 = (int)fminf(fmaxf(rintf(v1.y * QBF / den), -QBF), QBF);
    q2 = (int)fminf(fmaxf(rintf(v1.z * QBF / den), -QBF), QBF);
    q3 = (int)fminf(fmaxf(rintf(v1.w * QBF / den), -QBF), QBF);
    q[t + 256] = (q0 & 255) | ((q1 & 255) << 8) | ((q2 & 255) << 16) | ((q3 & 255) << 24);
}

// ---------- Kernel 2: gamma = sum(partial)/count ----------
__global__ __launch_bounds__(256) void k_gamma(const float* __restrict__ partial,
                                               float* __restrict__ gamma) {
    __shared__ float red[256];
    int t = threadIdx.x;
    float s = 0.f;
#pragma unroll
    for (int j = 0; j < 8; ++j) s += partial[t + j * 256];
    red[t] = s; __syncthreads();
    for (int off = 128; off > 0; off >>= 1) {
        if (t < off) red[t] += red[t + off];
        __syncthreads();
    }
    if (t == 0) gamma[0] = red[0] / 16777216.0f;
}

// ---------- Kernel 3: ternary-quantize W -> int8 ----------
__global__ __launch_bounds__(256) void k_quant_w(const float* __restrict__ w,
                                                 const float* __restrict__ gamma,
                                                 uint* __restrict__ wq) {
    float g = fmaxf(gamma[0], EPSF);
    int tid = blockIdx.x * 256 + threadIdx.x;    // 4,194,304 threads
    float4 v = ((const float4*)w)[tid];
    int a = (int)fminf(fmaxf(rintf(v.x / g), -1.f), 1.f);
    int b = (int)fminf(fmaxf(rintf(v.y / g), -1.f), 1.f);
    int c = (int)fminf(fmaxf(rintf(v.z / g), -1.f), 1.f);
    int d = (int)fminf(fmaxf(rintf(v.w / g), -1.f), 1.f);
    wq[tid] = (a & 255) | ((b & 255) << 8) | ((c & 255) << 16) | ((d & 255) << 24);
}

// ---------- Kernel 4: 256x128 i8 GEMM, ring-2, 3 blocks/CU ----------
// R12 loop (best known: 158us) with ring 3->2 (48KB LDS) so THREE independent
// blocks co-reside per CU (144KB <= 160KB; VGPR 112 <= 168 at 3 waves/SIMD).
// Mechanism: 3 desynced barrier groups — when one block's waves sit in the
// read/lgkm phase, the other two feed the MFMA pipes (the m97-family's proven
// ~3 blocks/CU regime). Ledger changes vs R12:
//   ring-2: top-of-iter vmcnt(0) retires stage(kt) — issued one full subtile
//   (~900+ cyc) earlier, xq/wq L2-resident -> near-free; barrier then
//   certifies all waves' stage(kt). stage(kt+1) issues AFTER that barrier into
//   slot (kt+1)&1 (= kt-1's slot, whose readers drained at their iter-(kt-1)
//   lgkmcnt(0), before reaching this barrier). All else identical to R12.
__global__ __launch_bounds__(256, 3) void k_gemm(const uint8_t* __restrict__ xq,
                                                 const uint8_t* __restrict__ wq,
                                                 const float* __restrict__ alpha,
                                                 const float* __restrict__ gamma,
                                                 float* __restrict__ out) {
    __shared__ __align__(16) char smem[49152];   // 2 ring slots x 24KB; epilogue reuse

    int bid = blockIdx.x;
    int wg = (bid & 7) * 256 + (bid >> 3);       // XCD-bijective (2048 % 8 == 0)
    int tm = wg >> 6, tn = wg & 63;              // 32 x 64 tiles of 256x128

    int t = threadIdx.x;
    int w = t >> 6, l = t & 63;
    int wr = w >> 1, wc = w & 1;                 // 2x2 waves, wave tile 128x64

    // ---- staging: 24 regions of 1KB (16 rows) per subtile, 6 per wave
    const uint8_t* srcb[6];
    int dstq[6];
    {
        int rsub = l >> 2;                       // row within 16-row region
        int clog = (l & 3) ^ ((rsub >> 1) & 3);  // pre-swizzled source chunk
#pragma unroll
        for (int j = 0; j < 6; ++j) {
            int q = w * 6 + j;                   // 0..23 (0-15 A, 16-23 B)
            int isB = q >> 4;
            int r = (isB ? (q & 7) : q) * 16 + rsub;
            int grow = isB ? tn * 128 + r : tm * 256 + r;
            srcb[j] = (isB ? wq : xq) + (size_t)grow * K_DIM + clog * 16;
            dstq[j] = q * 1024;                  // wave-uniform; hw adds l*16
        }
    }

    i32x4 acc[8][4];
#pragma unroll
    for (int m = 0; m < 8; ++m)
#pragma unroll
        for (int n = 0; n < 4; ++n) acc[m][n] = (i32x4){0, 0, 0, 0};

    int lrow = l & 15, kgrp = l >> 4;
    int cph = (kgrp ^ ((lrow >> 1) & 3)) * 16;   // swizzled read chunk
    int aoff[8], boff[4];
#pragma unroll
    for (int mf = 0; mf < 8; ++mf) aoff[mf] = (wr * 128 + mf * 16 + lrow) * 64 + cph;
#pragma unroll
    for (int nf = 0; nf < 4; ++nf) boff[nf] = 16384 + (wc * 64 + nf * 16 + lrow) * 64 + cph;

    // ---- prologue: stage sub-tile 0 only (6 issues/wave outstanding)
#pragma unroll
    for (int j = 0; j < 6; ++j)
        load_lds16(srcb[j], smem + dstq[j]);

    for (int kt = 0; kt < NT; ++kt) {
        char* sb = smem + (kt & 1) * 24576;
        // retire own stage(kt) (issued a full subtile ago), then certify all waves'
        asm volatile("s_waitcnt vmcnt(0)" ::: "memory");
        __builtin_amdgcn_s_barrier();

        i32x4 a[8], b[4];
        // oldest 8 DS ops: A0-3, B0-3
#pragma unroll
        for (int mf = 0; mf < 4; ++mf) a[mf] = *(const i32x4*)(sb + aoff[mf]);
#pragma unroll
        for (int nf = 0; nf < 4; ++nf) b[nf] = *(const i32x4*)(sb + boff[nf]);
        __builtin_amdgcn_sched_barrier(0);       // pin FIFO order
        // stage kt+1 into the other slot (freed: all waves drained before barrier)
        if (kt + 1 < NT) {
            char* db = smem + ((kt + 1) & 1) * 24576;
#pragma unroll
            for (int j = 0; j < 6; ++j)
                load_lds16(srcb[j] + (size_t)(kt + 1) * 64, db + dstq[j]);
        }
        __builtin_amdgcn_sched_barrier(0);
        // newest 4 DS ops: A4-7
#pragma unroll
        for (int mf = 4; mf < 8; ++mf) a[mf] = *(const i32x4*)(sb + aoff[mf]);

        asm volatile("s_waitcnt lgkmcnt(4)" ::: "memory");  // A0-3,B0-3 ready
        __builtin_amdgcn_sched_barrier(0);
        __builtin_amdgcn_s_setprio(1);
#pragma unroll
        for (int mf = 0; mf < 4; ++mf)
#pragma unroll
            for (int nf = 0; nf < 4; ++nf)
                acc[mf][nf] = __builtin_amdgcn_mfma_i32_16x16x64_i8(
                    a[mf], b[nf], acc[mf][nf], 0, 0, 0);
        __builtin_amdgcn_s_setprio(0);

        asm volatile("s_waitcnt lgkmcnt(0)" ::: "memory");
        __builtin_amdgcn_sched_barrier(0);
        __builtin_amdgcn_s_setprio(1);
#pragma unroll
        for (int mf = 4; mf < 8; ++mf)
#pragma unroll
            for (int nf = 0; nf < 4; ++nf)
                acc[mf][nf] = __builtin_amdgcn_mfma_i32_16x16x64_i8(
                    a[mf], b[nf], acc[mf][nf], 0, 0, 0);
        __builtin_amdgcn_s_setprio(0);
    }

    // ---- epilogue: LDS-transpose -> full-128B-line nontemporal f32x4 stores ----
    // C/D 16x16: col = lane&15, row = (lane>>4)*4 + reg.
    asm volatile("s_waitcnt lgkmcnt(0)" ::: "memory");
    __builtin_amdgcn_s_barrier();                // ring slots now safe to reuse
    float gs = gamma[0] / QBF;
    int orow0 = tm * 256 + wr * 128;
    int ocol0 = tn * 128 + wc * 64;
    int kgrp4 = kgrp * 4;
    char* ebase = smem + w * 8704;               // 4 waves x 8704 = 34816 <= 49152
#pragma unroll
    for (int mf = 0; mf < 8; ++mf) {
        float* eb = (float*)(ebase + (mf & 1) * 4352);
        int rbase = orow0 + mf * 16;
#pragma unroll
        for (int reg = 0; reg < 4; ++reg) {
            float s = alpha[rbase + kgrp4 + reg] * gs;
            int rowo = (kgrp4 + reg) * 68;
#pragma unroll
            for (int nf = 0; nf < 4; ++nf)
                eb[rowo + nf * 16 + lrow] = (float)acc[mf][nf][reg] * s;
        }
        asm volatile("s_waitcnt lgkmcnt(0)" ::: "memory");
        __builtin_amdgcn_sched_barrier(0);
#pragma unroll
        for (int pass = 0; pass < 4; ++pass) {
            int r16 = (pass >> 1) * 8 + (l >> 3);
            int fc  = (pass & 1) * 8 + (l & 7);
            f32x4 v = *(const f32x4*)(eb + r16 * 68 + fc * 4);
            __builtin_nontemporal_store(
                v, (f32x4*)(out + (size_t)(rbase + r16) * N_DIM + ocol0 + fc * 4));
        }
        asm volatile("s_waitcnt lgkmcnt(0)" ::: "memory");
        __builtin_amdgcn_sched_barrier(0);
    }
}

extern "C" void kernel_launch(void* const* d_in, const int* in_sizes, int n_in,
                              void* d_out, int out_size, void* d_ws, size_t ws_size,
                              hipStream_t stream) {
    const float* x  = (const float*)d_in[0];   // [4,2048,2048]
    const float* wt = (const float*)d_in[1];   // [8192,2048]
    float* out = (float*)d_out;                // [4,2048,8192] fp32

    char* ws = (char*)d_ws;
    uint8_t* xq     = (uint8_t*)ws;                     // 16,777,216 B
    uint8_t* wq     = (uint8_t*)(ws + 16777216);        // 16,777,216 B
    float* alpha    = (float*)(ws + 33554432);          // 32,768 B
    float* partial  = (float*)(ws + 33587200);          // 8,192 B
    float* gamma    = (float*)(ws + 33595392);          // 4 B

    k_prep<<<10240, 256, 0, stream>>>(x, wt, (uint*)xq, alpha, partial);
    k_gamma<<<1, 256, 0, stream>>>(partial, gamma);
    k_quant_w<<<16384, 256, 0, stream>>>(wt, gamma, (uint*)wq);
    k_gemm<<<2048, 256, 0, stream>>>(xq, wq, alpha, gamma, out);
}

// Round 18
// 202.767 us; speedup vs baseline: 2.7204x; 2.7204x over previous
//
#include <hip/hip_runtime.h>
#include <hip/hip_bf16.h>
#include <stdint.h>

typedef int i32x4 __attribute__((ext_vector_type(4)));
typedef float f32x4 __attribute__((ext_vector_type(4)));

#define K_DIM 2048
#define M_DIM 8192   // B*S = 4*2048 tokens
#define N_DIM 8192   // D_OUT
#define QBF   127.0f
#define EPSF  1e-5f
#define NT    32     // K_DIM / 64 sub-tiles (BK=64)

__device__ __forceinline__ void load_lds16(const void* gsrc, void* ldst) {
    __builtin_amdgcn_global_load_lds(
        (__attribute__((address_space(1))) void*)gsrc,
        (__attribute__((address_space(3))) void*)ldst,
        16, 0, 0);
}

// ---------- Kernel 1 (fused): blocks 0..8191 quantize x rows; 8192..10239 |W| sums --
__global__ __launch_bounds__(256) void k_prep(const float* __restrict__ x,
                                              const float* __restrict__ w,
                                              uint* __restrict__ xq,
                                              float* __restrict__ alpha,
                                              float* __restrict__ partial) {
    __shared__ float red[256];
    int t = threadIdx.x, bid = blockIdx.x;
    if (bid >= 8192) {
        // ---- |W| partial sums (deterministic) ----
        int b = bid - 8192;
        const float4* w4 = (const float4*)w;
        size_t base = (size_t)b * 2048;
        float s = 0.f;
#pragma unroll
        for (int j = 0; j < 8; ++j) {
            float4 v = w4[base + j * 256 + t];
            s += fabsf(v.x) + fabsf(v.y) + fabsf(v.z) + fabsf(v.w);
        }
        red[t] = s; __syncthreads();
        for (int off = 128; off > 0; off >>= 1) {
            if (t < off) red[t] += red[t + off];
            __syncthreads();
        }
        if (t == 0) partial[b] = red[0];
        return;
    }
    // ---- per-token absmax quantize ----
    int row = bid;
    const float4* x4 = (const float4*)x + (size_t)row * 512;
    float4 v0 = x4[t], v1 = x4[t + 256];
    float m = fmaxf(fmaxf(fabsf(v0.x), fabsf(v0.y)), fmaxf(fabsf(v0.z), fabsf(v0.w)));
    m = fmaxf(m, fmaxf(fmaxf(fabsf(v1.x), fabsf(v1.y)), fmaxf(fabsf(v1.z), fabsf(v1.w))));
    red[t] = m; __syncthreads();
    for (int off = 128; off > 0; off >>= 1) {
        if (t < off) red[t] = fmaxf(red[t], red[t + off]);
        __syncthreads();
    }
    float a = red[0];
    if (t == 0) alpha[row] = a;
    float den = fmaxf(a, EPSF);
    uint* q = xq + (size_t)row * 512;
    int q0 = (int)fminf(fmaxf(rintf(v0.x * QBF / den), -QBF), QBF);
    int q1 = (int)fminf(fmaxf(rintf(v0.y * QBF / den), -QBF), QBF);
    int q2 = (int)fminf(fmaxf(rintf(v0.z * QBF / den), -QBF), QBF);
    int q3 = (int)fminf(fmaxf(rintf(v0.w * QBF / den), -QBF), QBF);
    q[t] = (q0 & 255) | ((q1 & 255) << 8) | ((q2 & 255) << 16) | ((q3 & 255) << 24);
    q0 = (int)fminf(fmaxf(rintf(v1.x * QBF / den), -QBF), QBF);
    q1 = (int)fminf(fmaxf(rintf(v1.y * QBF / den), -QBF), QBF);
    q2 = (int)fminf(fmaxf(rintf(v1.z * QBF / den), -QBF), QBF);
    q3 = (int)fminf(fmaxf(rintf(v1.w * QBF / den), -QBF), QBF);
    q[t + 256] = (q0 & 255) | ((q1 & 255) << 8) | ((q2 & 255) << 16) | ((q3 & 255) << 24);
}

// ---------- Kernel 2: gamma = sum(partial)/count ----------
__global__ __launch_bounds__(256) void k_gamma(const float* __restrict__ partial,
                                               float* __restrict__ gamma) {
    __shared__ float red[256];
    int t = threadIdx.x;
    float s = 0.f;
#pragma unroll
    for (int j = 0; j < 8; ++j) s += partial[t + j * 256];
    red[t] = s; __syncthreads();
    for (int off = 128; off > 0; off >>= 1) {
        if (t < off) red[t] += red[t + off];
        __syncthreads();
    }
    if (t == 0) gamma[0] = red[0] / 16777216.0f;
}

// ---------- Kernel 3: ternary-quantize W -> int8 ----------
__global__ __launch_bounds__(256) void k_quant_w(const float* __restrict__ w,
                                                 const float* __restrict__ gamma,
                                                 uint* __restrict__ wq) {
    float g = fmaxf(gamma[0], EPSF);
    int tid = blockIdx.x * 256 + threadIdx.x;    // 4,194,304 threads
    float4 v = ((const float4*)w)[tid];
    int a = (int)fminf(fmaxf(rintf(v.x / g), -1.f), 1.f);
    int b = (int)fminf(fmaxf(rintf(v.y / g), -1.f), 1.f);
    int c = (int)fminf(fmaxf(rintf(v.z / g), -1.f), 1.f);
    int d = (int)fminf(fmaxf(rintf(v.w / g), -1.f), 1.f);
    wq[tid] = (a & 255) | ((b & 255) << 8) | ((c & 255) << 16) | ((d & 255) << 24);
}

// ---------- Kernel 4: 256x128 i8 GEMM, ring-2, 3 blocks/CU (by LDS), no spill ----
// R17 retest without the confound: launch_bounds(256,2) keeps the R12 register
// budget (VGPR ~112, zero spill — R17's (256,3) forced 84 VGPR and spilled the
// 128-reg accumulator: WRITE 1.05GB, 541us). Ring-2 = 48KB LDS -> 3 blocks/CU
// resident BY LDS (147KB <= 160KB); 12 waves/CU. Three independent barrier
// groups interleave read/MFMA phases (the occupancy hypothesis, now unconfounded).
// Ledger: top-of-iter vmcnt(0) retires own stage(kt) (issued one subtile ago,
// xq/wq L2-resident -> short wait); barrier certifies all waves' stage(kt);
// stage(kt+1) issues after the barrier into slot (kt+1)&1, whose readers
// drained at their iter-(kt-1) lgkmcnt(0). lgkm split 4/0 as in R12.
__global__ __launch_bounds__(256, 2) void k_gemm(const uint8_t* __restrict__ xq,
                                                 const uint8_t* __restrict__ wq,
                                                 const float* __restrict__ alpha,
                                                 const float* __restrict__ gamma,
                                                 float* __restrict__ out) {
    __shared__ __align__(16) char smem[49152];   // 2 ring slots x 24KB; epilogue reuse

    int bid = blockIdx.x;
    int wg = (bid & 7) * 256 + (bid >> 3);       // XCD-bijective (2048 % 8 == 0)
    int tm = wg >> 6, tn = wg & 63;              // 32 x 64 tiles of 256x128

    int t = threadIdx.x;
    int w = t >> 6, l = t & 63;
    int wr = w >> 1, wc = w & 1;                 // 2x2 waves, wave tile 128x64

    // ---- staging: 24 regions of 1KB (16 rows) per subtile, 6 per wave
    const uint8_t* srcb[6];
    int dstq[6];
    {
        int rsub = l >> 2;                       // row within 16-row region
        int clog = (l & 3) ^ ((rsub >> 1) & 3);  // pre-swizzled source chunk
#pragma unroll
        for (int j = 0; j < 6; ++j) {
            int q = w * 6 + j;                   // 0..23 (0-15 A, 16-23 B)
            int isB = q >> 4;
            int r = (isB ? (q & 7) : q) * 16 + rsub;
            int grow = isB ? tn * 128 + r : tm * 256 + r;
            srcb[j] = (isB ? wq : xq) + (size_t)grow * K_DIM + clog * 16;
            dstq[j] = q * 1024;                  // wave-uniform; hw adds l*16
        }
    }

    i32x4 acc[8][4];
#pragma unroll
    for (int m = 0; m < 8; ++m)
#pragma unroll
        for (int n = 0; n < 4; ++n) acc[m][n] = (i32x4){0, 0, 0, 0};

    int lrow = l & 15, kgrp = l >> 4;
    int cph = (kgrp ^ ((lrow >> 1) & 3)) * 16;   // swizzled read chunk
    int aoff[8], boff[4];
#pragma unroll
    for (int mf = 0; mf < 8; ++mf) aoff[mf] = (wr * 128 + mf * 16 + lrow) * 64 + cph;
#pragma unroll
    for (int nf = 0; nf < 4; ++nf) boff[nf] = 16384 + (wc * 64 + nf * 16 + lrow) * 64 + cph;

    // ---- prologue: stage sub-tile 0 only (6 issues/wave outstanding)
#pragma unroll
    for (int j = 0; j < 6; ++j)
        load_lds16(srcb[j], smem + dstq[j]);

    for (int kt = 0; kt < NT; ++kt) {
        char* sb = smem + (kt & 1) * 24576;
        // retire own stage(kt) (issued a full subtile ago), then certify all waves'
        asm volatile("s_waitcnt vmcnt(0)" ::: "memory");
        __builtin_amdgcn_s_barrier();

        i32x4 a[8], b[4];
        // oldest 8 DS ops: A0-3, B0-3
#pragma unroll
        for (int mf = 0; mf < 4; ++mf) a[mf] = *(const i32x4*)(sb + aoff[mf]);
#pragma unroll
        for (int nf = 0; nf < 4; ++nf) b[nf] = *(const i32x4*)(sb + boff[nf]);
        __builtin_amdgcn_sched_barrier(0);       // pin FIFO order
        // stage kt+1 into the other slot (freed: all waves drained before barrier)
        if (kt + 1 < NT) {
            char* db = smem + ((kt + 1) & 1) * 24576;
#pragma unroll
            for (int j = 0; j < 6; ++j)
                load_lds16(srcb[j] + (size_t)(kt + 1) * 64, db + dstq[j]);
        }
        __builtin_amdgcn_sched_barrier(0);
        // newest 4 DS ops: A4-7
#pragma unroll
        for (int mf = 4; mf < 8; ++mf) a[mf] = *(const i32x4*)(sb + aoff[mf]);

        asm volatile("s_waitcnt lgkmcnt(4)" ::: "memory");  // A0-3,B0-3 ready
        __builtin_amdgcn_sched_barrier(0);
        __builtin_amdgcn_s_setprio(1);
#pragma unroll
        for (int mf = 0; mf < 4; ++mf)
#pragma unroll
            for (int nf = 0; nf < 4; ++nf)
                acc[mf][nf] = __builtin_amdgcn_mfma_i32_16x16x64_i8(
                    a[mf], b[nf], acc[mf][nf], 0, 0, 0);
        __builtin_amdgcn_s_setprio(0);

        asm volatile("s_waitcnt lgkmcnt(0)" ::: "memory");
        __builtin_amdgcn_sched_barrier(0);
        __builtin_amdgcn_s_setprio(1);
#pragma unroll
        for (int mf = 4; mf < 8; ++mf)
#pragma unroll
            for (int nf = 0; nf < 4; ++nf)
                acc[mf][nf] = __builtin_amdgcn_mfma_i32_16x16x64_i8(
                    a[mf], b[nf], acc[mf][nf], 0, 0, 0);
        __builtin_amdgcn_s_setprio(0);
    }

    // ---- epilogue: LDS-transpose -> full-128B-line nontemporal f32x4 stores ----
    // C/D 16x16: col = lane&15, row = (lane>>4)*4 + reg.
    asm volatile("s_waitcnt lgkmcnt(0)" ::: "memory");
    __builtin_amdgcn_s_barrier();                // ring slots now safe to reuse
    float gs = gamma[0] / QBF;
    int orow0 = tm * 256 + wr * 128;
    int ocol0 = tn * 128 + wc * 64;
    int kgrp4 = kgrp * 4;
    char* ebase = smem + w * 8704;               // 4 waves x 8704 = 34816 <= 49152
#pragma unroll
    for (int mf = 0; mf < 8; ++mf) {
        float* eb = (float*)(ebase + (mf & 1) * 4352);
        int rbase = orow0 + mf * 16;
#pragma unroll
        for (int reg = 0; reg < 4; ++reg) {
            float s = alpha[rbase + kgrp4 + reg] * gs;
            int rowo = (kgrp4 + reg) * 68;
#pragma unroll
            for (int nf = 0; nf < 4; ++nf)
                eb[rowo + nf * 16 + lrow] = (float)acc[mf][nf][reg] * s;
        }
        asm volatile("s_waitcnt lgkmcnt(0)" ::: "memory");
        __builtin_amdgcn_sched_barrier(0);
#pragma unroll
        for (int pass = 0; pass < 4; ++pass) {
            int r16 = (pass >> 1) * 8 + (l >> 3);
            int fc  = (pass & 1) * 8 + (l & 7);
            f32x4 v = *(const f32x4*)(eb + r16 * 68 + fc * 4);
            __builtin_nontemporal_store(
                v, (f32x4*)(out + (size_t)(rbase + r16) * N_DIM + ocol0 + fc * 4));
        }
        asm volatile("s_waitcnt lgkmcnt(0)" ::: "memory");
        __builtin_amdgcn_sched_barrier(0);
    }
}

extern "C" void kernel_launch(void* const* d_in, const int* in_sizes, int n_in,
                              void* d_out, int out_size, void* d_ws, size_t ws_size,
                              hipStream_t stream) {
    const float* x  = (const float*)d_in[0];   // [4,2048,2048]
    const float* wt = (const float*)d_in[1];   // [8192,2048]
    float* out = (float*)d_out;                // [4,2048,8192] fp32

    char* ws = (char*)d_ws;
    uint8_t* xq     = (uint8_t*)ws;                     // 16,777,216 B
    uint8_t* wq     = (uint8_t*)(ws + 16777216);        // 16,777,216 B
    float* alpha    = (float*)(ws + 33554432);          // 32,768 B
    float* partial  = (float*)(ws + 33587200);          // 8,192 B
    float* gamma    = (float*)(ws + 33595392);          // 4 B

    k_prep<<<10240, 256, 0, stream>>>(x, wt, (uint*)xq, alpha, partial);
    k_gamma<<<1, 256, 0, stream>>>(partial, gamma);
    k_quant_w<<<16384, 256, 0, stream>>>(wt, gamma, (uint*)wq);
    k_gemm<<<2048, 256, 0, stream>>>(xq, wq, alpha, gamma, out);
}

// Round 19
// 198.950 us; speedup vs baseline: 2.7725x; 1.0192x over previous
//
#include <hip/hip_runtime.h>
#include <hip/hip_bf16.h>
#include <stdint.h>

typedef int i32x4 __attribute__((ext_vector_type(4)));
typedef float f32x4 __attribute__((ext_vector_type(4)));

#define K_DIM 2048
#define M_DIM 8192   // B*S = 4*2048 tokens
#define N_DIM 8192   // D_OUT
#define QBF   127.0f
#define EPSF  1e-5f
#define NT    32     // K_DIM / 64 sub-tiles (BK=64)

__device__ __forceinline__ void load_lds16(const void* gsrc, void* ldst) {
    __builtin_amdgcn_global_load_lds(
        (__attribute__((address_space(1))) void*)gsrc,
        (__attribute__((address_space(3))) void*)ldst,
        16, 0, 0);
}

// ---------- Kernel 1 (fused): blocks 0..8191 quantize x rows; 8192..10239 |W| sums --
__global__ __launch_bounds__(256) void k_prep(const float* __restrict__ x,
                                              const float* __restrict__ w,
                                              uint* __restrict__ xq,
                                              float* __restrict__ alpha,
                                              float* __restrict__ partial) {
    __shared__ float red[256];
    int t = threadIdx.x, bid = blockIdx.x;
    if (bid >= 8192) {
        // ---- |W| partial sums (deterministic) ----
        int b = bid - 8192;
        const float4* w4 = (const float4*)w;
        size_t base = (size_t)b * 2048;
        float s = 0.f;
#pragma unroll
        for (int j = 0; j < 8; ++j) {
            float4 v = w4[base + j * 256 + t];
            s += fabsf(v.x) + fabsf(v.y) + fabsf(v.z) + fabsf(v.w);
        }
        red[t] = s; __syncthreads();
        for (int off = 128; off > 0; off >>= 1) {
            if (t < off) red[t] += red[t + off];
            __syncthreads();
        }
        if (t == 0) partial[b] = red[0];
        return;
    }
    // ---- per-token absmax quantize ----
    int row = bid;
    const float4* x4 = (const float4*)x + (size_t)row * 512;
    float4 v0 = x4[t], v1 = x4[t + 256];
    float m = fmaxf(fmaxf(fabsf(v0.x), fabsf(v0.y)), fmaxf(fabsf(v0.z), fabsf(v0.w)));
    m = fmaxf(m, fmaxf(fmaxf(fabsf(v1.x), fabsf(v1.y)), fmaxf(fabsf(v1.z), fabsf(v1.w))));
    red[t] = m; __syncthreads();
    for (int off = 128; off > 0; off >>= 1) {
        if (t < off) red[t] = fmaxf(red[t], red[t + off]);
        __syncthreads();
    }
    float a = red[0];
    if (t == 0) alpha[row] = a;
    float den = fmaxf(a, EPSF);
    uint* q = xq + (size_t)row * 512;
    int q0 = (int)fminf(fmaxf(rintf(v0.x * QBF / den), -QBF), QBF);
    int q1 = (int)fminf(fmaxf(rintf(v0.y * QBF / den), -QBF), QBF);
    int q2 = (int)fminf(fmaxf(rintf(v0.z * QBF / den), -QBF), QBF);
    int q3 = (int)fminf(fmaxf(rintf(v0.w * QBF / den), -QBF), QBF);
    q[t] = (q0 & 255) | ((q1 & 255) << 8) | ((q2 & 255) << 16) | ((q3 & 255) << 24);
    q0 = (int)fminf(fmaxf(rintf(v1.x * QBF / den), -QBF), QBF);
    q1 = (int)fminf(fmaxf(rintf(v1.y * QBF / den), -QBF), QBF);
    q2 = (int)fminf(fmaxf(rintf(v1.z * QBF / den), -QBF), QBF);
    q3 = (int)fminf(fmaxf(rintf(v1.w * QBF / den), -QBF), QBF);
    q[t + 256] = (q0 & 255) | ((q1 & 255) << 8) | ((q2 & 255) << 16) | ((q3 & 255) << 24);
}

// ---------- Kernel 2: gamma = sum(partial)/count ----------
__global__ __launch_bounds__(256) void k_gamma(const float* __restrict__ partial,
                                               float* __restrict__ gamma) {
    __shared__ float red[256];
    int t = threadIdx.x;
    float s = 0.f;
#pragma unroll
    for (int j = 0; j < 8; ++j) s += partial[t + j * 256];
    red[t] = s; __syncthreads();
    for (int off = 128; off > 0; off >>= 1) {
        if (t < off) red[t] += red[t + off];
        __syncthreads();
    }
    if (t == 0) gamma[0] = red[0] / 16777216.0f;
}

// ---------- Kernel 3: ternary-quantize W -> int8 ----------
__global__ __launch_bounds__(256) void k_quant_w(const float* __restrict__ w,
                                                 const float* __restrict__ gamma,
                                                 uint* __restrict__ wq) {
    float g = fmaxf(gamma[0], EPSF);
    int tid = blockIdx.x * 256 + threadIdx.x;    // 4,194,304 threads
    float4 v = ((const float4*)w)[tid];
    int a = (int)fminf(fmaxf(rintf(v.x / g), -1.f), 1.f);
    int b = (int)fminf(fmaxf(rintf(v.y / g), -1.f), 1.f);
    int c = (int)fminf(fmaxf(rintf(v.z / g), -1.f), 1.f);
    int d = (int)fminf(fmaxf(rintf(v.w / g), -1.f), 1.f);
    wq[tid] = (a & 255) | ((b & 255) << 8) | ((c & 255) << 16) | ((d & 255) << 24);
}

// ---------- Kernel 4: 256x128 i8 GEMM (R8 loop) + full-line nt epilogue ----------
// Best measured configuration (R16: k_gemm 158us, total 199.2us). 256 thr =
// 4 waves (2x2), wave tile 128x64, BK=64, ring 3x24KB, 2 blocks/CU, 0-conflict
// swizzle phys_chunk = logical ^ ((row>>1)&3). One barrier per subtile, counted
// vmcnt(6) (never 0 mid-loop — R18 showed full-drain costs ~8us), lgkm split
// 4/0 across two 16-MFMA clusters. Epilogue transposes through LDS (stride 68
// dwords -> 2-way banks = free) to f32x4/lane full-128B-line nt stores.
// Session plateau evidence: ten schedule structures (1/2/3 blocks-per-CU,
// reg-prefetch, fine-phase, barrier-free, B-in-regs x2, 32x32) all land
// 158-188us at MfmaUtil 31-39% — per-CU-subtile LDS movement + barrier
// phase-lock serializes with the ~653-cyc MFMA burst (sum, not max).
__global__ __launch_bounds__(256, 2) void k_gemm(const uint8_t* __restrict__ xq,
                                                 const uint8_t* __restrict__ wq,
                                                 const float* __restrict__ alpha,
                                                 const float* __restrict__ gamma,
                                                 float* __restrict__ out) {
    __shared__ __align__(16) char smem[73728];   // 3 ring slots x 24KB; epilogue reuse

    int bid = blockIdx.x;
    int wg = (bid & 7) * 256 + (bid >> 3);       // XCD-bijective (2048 % 8 == 0)
    int tm = wg >> 6, tn = wg & 63;              // 32 x 64 tiles of 256x128

    int t = threadIdx.x;
    int w = t >> 6, l = t & 63;
    int wr = w >> 1, wc = w & 1;                 // 2x2 waves, wave tile 128x64

    // ---- staging: 24 regions of 1KB (16 rows) per subtile, 6 per wave
    const uint8_t* srcb[6];
    int dstq[6];
    {
        int rsub = l >> 2;                       // row within 16-row region
        int clog = (l & 3) ^ ((rsub >> 1) & 3);  // pre-swizzled source chunk
#pragma unroll
        for (int j = 0; j < 6; ++j) {
            int q = w * 6 + j;                   // 0..23 (0-15 A, 16-23 B)
            int isB = q >> 4;
            int r = (isB ? (q & 7) : q) * 16 + rsub;
            int grow = isB ? tn * 128 + r : tm * 256 + r;
            srcb[j] = (isB ? wq : xq) + (size_t)grow * K_DIM + clog * 16;
            dstq[j] = q * 1024;                  // wave-uniform; hw adds l*16
        }
    }

    i32x4 acc[8][4];
#pragma unroll
    for (int m = 0; m < 8; ++m)
#pragma unroll
        for (int n = 0; n < 4; ++n) acc[m][n] = (i32x4){0, 0, 0, 0};

    int lrow = l & 15, kgrp = l >> 4;
    int cph = (kgrp ^ ((lrow >> 1) & 3)) * 16;   // swizzled read chunk
    int aoff[8], boff[4];
#pragma unroll
    for (int mf = 0; mf < 8; ++mf) aoff[mf] = (wr * 128 + mf * 16 + lrow) * 64 + cph;
#pragma unroll
    for (int nf = 0; nf < 4; ++nf) boff[nf] = 16384 + (wc * 64 + nf * 16 + lrow) * 64 + cph;

    // ---- prologue: stage sub-tiles 0,1 (12 issues/wave outstanding)
#pragma unroll
    for (int p = 0; p < 2; ++p)
#pragma unroll
        for (int j = 0; j < 6; ++j)
            load_lds16(srcb[j] + (size_t)p * 64, smem + p * 24576 + dstq[j]);

    int slot = 0;
    for (int kt = 0; kt < NT; ++kt) {
        char* sb = smem + slot * 24576;
        if (kt < NT - 1) asm volatile("s_waitcnt vmcnt(6)" ::: "memory");
        else             asm volatile("s_waitcnt vmcnt(0)" ::: "memory");
        __builtin_amdgcn_s_barrier();

        i32x4 a[8], b[4];
        // oldest 8 DS ops: A0-3, B0-3
#pragma unroll
        for (int mf = 0; mf < 4; ++mf) a[mf] = *(const i32x4*)(sb + aoff[mf]);
#pragma unroll
        for (int nf = 0; nf < 4; ++nf) b[nf] = *(const i32x4*)(sb + boff[nf]);
        __builtin_amdgcn_sched_barrier(0);       // pin FIFO order
        // stage kt+2 into slot (kt+2)%3 (freed: all waves drained before barrier)
        if (kt + 2 < NT) {
            int ds = slot + 2; if (ds >= 3) ds -= 3;
            char* db = smem + ds * 24576;
#pragma unroll
            for (int j = 0; j < 6; ++j)
                load_lds16(srcb[j] + (size_t)(kt + 2) * 64, db + dstq[j]);
        }
        __builtin_amdgcn_sched_barrier(0);
        // newest 4 DS ops: A4-7
#pragma unroll
        for (int mf = 4; mf < 8; ++mf) a[mf] = *(const i32x4*)(sb + aoff[mf]);

        asm volatile("s_waitcnt lgkmcnt(4)" ::: "memory");  // A0-3,B0-3 ready
        __builtin_amdgcn_sched_barrier(0);
        __builtin_amdgcn_s_setprio(1);
#pragma unroll
        for (int mf = 0; mf < 4; ++mf)
#pragma unroll
            for (int nf = 0; nf < 4; ++nf)
                acc[mf][nf] = __builtin_amdgcn_mfma_i32_16x16x64_i8(
                    a[mf], b[nf], acc[mf][nf], 0, 0, 0);
        __builtin_amdgcn_s_setprio(0);

        asm volatile("s_waitcnt lgkmcnt(0)" ::: "memory");
        __builtin_amdgcn_sched_barrier(0);
        __builtin_amdgcn_s_setprio(1);
#pragma unroll
        for (int mf = 4; mf < 8; ++mf)
#pragma unroll
            for (int nf = 0; nf < 4; ++nf)
                acc[mf][nf] = __builtin_amdgcn_mfma_i32_16x16x64_i8(
                    a[mf], b[nf], acc[mf][nf], 0, 0, 0);
        __builtin_amdgcn_s_setprio(0);

        slot = (slot == 2) ? 0 : slot + 1;
    }

    // ---- epilogue: LDS-transpose -> full-128B-line nontemporal f32x4 stores ----
    // C/D 16x16: col = lane&15, row = (lane>>4)*4 + reg.
    asm volatile("s_waitcnt lgkmcnt(0)" ::: "memory");
    __builtin_amdgcn_s_barrier();                // ring slots now safe to reuse
    float gs = gamma[0] / QBF;
    int orow0 = tm * 256 + wr * 128;
    int ocol0 = tn * 128 + wc * 64;
    int kgrp4 = kgrp * 4;
    char* ebase = smem + w * 8704;
#pragma unroll
    for (int mf = 0; mf < 8; ++mf) {
        float* eb = (float*)(ebase + (mf & 1) * 4352);
        int rbase = orow0 + mf * 16;
#pragma unroll
        for (int reg = 0; reg < 4; ++reg) {
            float s = alpha[rbase + kgrp4 + reg] * gs;
            int rowo = (kgrp4 + reg) * 68;
#pragma unroll
            for (int nf = 0; nf < 4; ++nf)
                eb[rowo + nf * 16 + lrow] = (float)acc[mf][nf][reg] * s;
        }
        asm volatile("s_waitcnt lgkmcnt(0)" ::: "memory");
        __builtin_amdgcn_sched_barrier(0);
#pragma unroll
        for (int pass = 0; pass < 4; ++pass) {
            int r16 = (pass >> 1) * 8 + (l >> 3);
            int fc  = (pass & 1) * 8 + (l & 7);
            f32x4 v = *(const f32x4*)(eb + r16 * 68 + fc * 4);
            __builtin_nontemporal_store(
                v, (f32x4*)(out + (size_t)(rbase + r16) * N_DIM + ocol0 + fc * 4));
        }
        asm volatile("s_waitcnt lgkmcnt(0)" ::: "memory");
        __builtin_amdgcn_sched_barrier(0);
    }
}

extern "C" void kernel_launch(void* const* d_in, const int* in_sizes, int n_in,
                              void* d_out, int out_size, void* d_ws, size_t ws_size,
                              hipStream_t stream) {
    const float* x  = (const float*)d_in[0];   // [4,2048,2048]
    const float* wt = (const float*)d_in[1];   // [8192,2048]
    float* out = (float*)d_out;                // [4,2048,8192] fp32

    char* ws = (char*)d_ws;
    uint8_t* xq     = (uint8_t*)ws;                     // 16,777,216 B
    uint8_t* wq     = (uint8_t*)(ws + 16777216);        // 16,777,216 B
    float* alpha    = (float*)(ws + 33554432);          // 32,768 B
    float* partial  = (float*)(ws + 33587200);          // 8,192 B
    float* gamma    = (float*)(ws + 33595392);          // 4 B

    k_prep<<<10240, 256, 0, stream>>>(x, wt, (uint*)xq, alpha, partial);
    k_gamma<<<1, 256, 0, stream>>>(partial, gamma);
    k_quant_w<<<16384, 256, 0, stream>>>(wt, gamma, (uint*)wq);
    k_gemm<<<2048, 256, 0, stream>>>(xq, wq, alpha, gamma, out);
}